// Round 8
// baseline (143.350 us; speedup 1.0000x reference)
//
#include <hip/hip_runtime.h>
#include <hip/hip_bf16.h>
#include <math.h>

#define TAU_INV_LOG2E 14.4269504088896340736f  // (1/0.1) * log2(e)
#define EPS 1e-8f

typedef __attribute__((ext_vector_type(8))) short bf16x8;
typedef __attribute__((ext_vector_type(8))) unsigned short u16x8;
typedef __attribute__((ext_vector_type(4))) float f32x4;

static __device__ __forceinline__ unsigned short f2bf(float f) {
    unsigned int u = __float_as_uint(f);
    unsigned int r = (u + 0x7fffu + ((u >> 16) & 1u)) >> 16;
    return (unsigned short)r;
}

// Kernel 1: L2-normalize rows AND repack into fragment-native layout xf.
// xf unit (rt, kc, lane): 16B at ((rt*8+kc)*64 + lane)*8 shorts holding
//   xn[rt*16 + (lane&15)][kc*32 + (lane>>4)*8 .. +7]
// so a gemm wave loads an entire MFMA fragment with ONE coalesced
// global_load_dwordx4 (64 lanes x 16B contiguous = 1KB).
// Block = 16 rows (one rt group), 256 threads: thread t -> row t>>4,
// 16-float chunk t&15. Row norm via shfl over the 16-lane row group.
__global__ __launch_bounds__(256) void normalize_repack_kernel(
    const float* __restrict__ x, unsigned short* __restrict__ xf,
    float* __restrict__ out, int N) {
    __shared__ unsigned short xs[16 * 264];  // stride 264 shorts (pad: 2-way banks)
    const int t   = threadIdx.x;
    const int rt  = blockIdx.x;
    const int r   = t >> 4;
    const int c16 = t & 15;
    if (rt == 0 && t == 0) out[0] = 0.0f;

    const float* xr = x + ((size_t)rt * 16 + r) * 256 + c16 * 16;
    const float4 v0 = ((const float4*)xr)[0];
    const float4 v1 = ((const float4*)xr)[1];
    const float4 v2 = ((const float4*)xr)[2];
    const float4 v3 = ((const float4*)xr)[3];
    float s = v0.x*v0.x + v0.y*v0.y + v0.z*v0.z + v0.w*v0.w
            + v1.x*v1.x + v1.y*v1.y + v1.z*v1.z + v1.w*v1.w
            + v2.x*v2.x + v2.y*v2.y + v2.z*v2.z + v2.w*v2.w
            + v3.x*v3.x + v3.y*v3.y + v3.z*v3.z + v3.w*v3.w;
    // reduce across the 16 threads of this row (consecutive lanes, xor-closed)
    s += __shfl_xor(s, 1);
    s += __shfl_xor(s, 2);
    s += __shfl_xor(s, 4);
    s += __shfl_xor(s, 8);
    const float rinv = 1.0f / fmaxf(sqrtf(s), 1e-12f);

    u16x8 w0, w1;
    w0[0] = f2bf(v0.x * rinv); w0[1] = f2bf(v0.y * rinv);
    w0[2] = f2bf(v0.z * rinv); w0[3] = f2bf(v0.w * rinv);
    w0[4] = f2bf(v1.x * rinv); w0[5] = f2bf(v1.y * rinv);
    w0[6] = f2bf(v1.z * rinv); w0[7] = f2bf(v1.w * rinv);
    w1[0] = f2bf(v2.x * rinv); w1[1] = f2bf(v2.y * rinv);
    w1[2] = f2bf(v2.z * rinv); w1[3] = f2bf(v2.w * rinv);
    w1[4] = f2bf(v3.x * rinv); w1[5] = f2bf(v3.y * rinv);
    w1[6] = f2bf(v3.z * rinv); w1[7] = f2bf(v3.w * rinv);
    *(u16x8*)(&xs[r * 264 + c16 * 16 + 0]) = w0;
    *(u16x8*)(&xs[r * 264 + c16 * 16 + 8]) = w1;
    __syncthreads();

    // write phase: thread t emits units u = t and t+256 of this rt's 8KB block
    #pragma unroll
    for (int uu = 0; uu < 2; ++uu) {
        const int u   = t + uu * 256;         // 0..511
        const int kc  = u >> 6;
        const int ln  = u & 63;
        const int q   = ln >> 4;
        const int l16 = ln & 15;
        const u16x8 d = *(const u16x8*)(&xs[l16 * 264 + kc * 32 + q * 8]);
        *(u16x8*)(xf + (size_t)rt * 4096 + (size_t)u * 8) = d;
    }
}

// Kernel 2: symmetric fused S = Xn*Xn^T on upper-triangle 128x128 tiles.
// NO LDS, NO barriers: fragments are loaded straight from the fragment-native
// xf with perfectly-coalesced dwordx4 loads (xf = 4MB, fits each XCD's L2).
// 128 threads = 2 waves; wave w computes all 128 rows x its 64-col half
// (acc 8x4 f32x4 = 128 AGPR). 12 independent loads + 32 MFMA per kc, 8 kc --
// compiler pipelines freely (no sync points), 4 blocks/CU hide L2 latency.
// Atomic-free epilogue slots (unique writer per cell):
//   row-partials (64 cols of wave w)  -> prowR[2*bj+w],  rows of bi
//   col-partials (full 128-row sums)  -> prowC[bi],      rows of bj (!diag)
__global__ __launch_bounds__(128, 2) void gemm_frag_kernel(
    const unsigned short* __restrict__ xf, float* __restrict__ prowR,
    float* __restrict__ prowC, int N) {
    const int tid  = threadIdx.x;
    const int w    = tid >> 6;
    const int lane = tid & 63;
    const int quad = lane >> 4;
    const int l16  = lane & 15;

    // decode upper-triangle tile pair (bi <= bj) from 1D block index
    const int B = N >> 7;  // 64
    const int t = blockIdx.x;
    int bi = (int)((2.0 * B + 1.0 -
                    sqrt((2.0 * B + 1.0) * (2.0 * B + 1.0) - 8.0 * (double)t)) * 0.5);
    while (bi > 0 && t < bi * B - (bi * (bi - 1)) / 2) --bi;
    while (t >= (bi + 1) * B - ((bi + 1) * bi) / 2) ++bi;
    const int bj = bi + (t - (bi * B - (bi * (bi - 1)) / 2));
    const bool diag = (bi == bj);

    const size_t lane8 = (size_t)lane * 8;
    const unsigned short* Ab = xf + (size_t)(bi * 8) * 4096;          // rt = bi*8+mt
    const unsigned short* Bb = xf + (size_t)(bj * 8 + w * 4) * 4096;  // rt = .. + nt

    f32x4 acc[8][4];
    #pragma unroll
    for (int mt = 0; mt < 8; ++mt)
        #pragma unroll
        for (int nt = 0; nt < 4; ++nt)
            acc[mt][nt] = (f32x4){0.f, 0.f, 0.f, 0.f};

    #pragma unroll
    for (int kc = 0; kc < 8; ++kc) {
        bf16x8 a[8], b[4];
        #pragma unroll
        for (int mt = 0; mt < 8; ++mt)
            a[mt] = *(const bf16x8*)(Ab + ((size_t)mt * 8 + kc) * 512 + lane8);
        #pragma unroll
        for (int nt = 0; nt < 4; ++nt)
            b[nt] = *(const bf16x8*)(Bb + ((size_t)nt * 8 + kc) * 512 + lane8);
        #pragma unroll
        for (int mt = 0; mt < 8; ++mt)
            #pragma unroll
            for (int nt = 0; nt < 4; ++nt)
                acc[mt][nt] = __builtin_amdgcn_mfma_f32_16x16x32_bf16(
                    a[mt], b[nt], acc[mt][nt], 0, 0, 0);
    }

    // Epilogue. C/D layout: col = l16, row = quad*4 + reg  [m89/m91]
    const int iBase = bi * 128;
    const int jBase = bj * 128;
    float rsum[8][4];
    float csum[4] = {0.f, 0.f, 0.f, 0.f};
    #pragma unroll
    for (int mt = 0; mt < 8; ++mt)
        #pragma unroll
        for (int r = 0; r < 4; ++r) rsum[mt][r] = 0.f;

    #pragma unroll
    for (int mt = 0; mt < 8; ++mt) {
        const int gi0 = iBase + mt * 16 + quad * 4;
        #pragma unroll
        for (int nt = 0; nt < 4; ++nt) {
            const int gj = jBase + w * 64 + nt * 16 + l16;
            #pragma unroll
            for (int r = 0; r < 4; ++r) {
                float e = __builtin_amdgcn_exp2f(acc[mt][nt][r] * TAU_INV_LOG2E);
                if (gi0 + r == gj) e = 0.0f;  // diagonal (diag tiles only)
                rsum[mt][r] += e;
                csum[nt] += e;
            }
        }
    }
    // row partials (this wave's 64 cols) -> prowR slot 2*bj+w, rows of bi
    {
        float* slot = prowR + (size_t)(2 * bj + w) * N;
        #pragma unroll
        for (int mt = 0; mt < 8; ++mt) {
            const int gi0 = iBase + mt * 16 + quad * 4;
            #pragma unroll
            for (int r = 0; r < 4; ++r) {
                float s = rsum[mt][r];
                s += __shfl_xor(s, 1);
                s += __shfl_xor(s, 2);
                s += __shfl_xor(s, 4);
                s += __shfl_xor(s, 8);
                if (l16 == 0) slot[gi0 + r] = s;
            }
        }
    }
    // col partials (full 128-row sums; symmetry) -> prowC slot bi, rows of bj
    if (!diag) {
        float* slot = prowC + (size_t)bi * N;
        #pragma unroll
        for (int nt = 0; nt < 4; ++nt) {
            float s = csum[nt];
            s += __shfl_xor(s, 16);
            s += __shfl_xor(s, 32);
            if (quad == 0)
                slot[jBase + w * 64 + nt * 16 + l16] = s;
        }
    }
}

// Kernel 3: row i (block a = i>>7): rowsum_i = sum prowR[p>=2a] + prowC[p<a];
// loss += log(rowsum/(N-1)+eps)/N. 32 blocks x 256 threads (a wave-uniform).
__global__ __launch_bounds__(256) void finalize_kernel(
    const float* __restrict__ prowR, const float* __restrict__ prowC,
    float* __restrict__ out, int N) {
    __shared__ float red[4];
    const int i = blockIdx.x * 256 + threadIdx.x;
    const int a = i >> 7;
    float s = 0.f;
    for (int p = 2 * a; p < 128; ++p) s += prowR[(size_t)p * N + i];
    for (int p = 0; p < a; ++p)       s += prowC[(size_t)p * N + i];
    float acc = logf(fmaf(s, 1.0f / (float)(N - 1), EPS));
    acc += __shfl_xor(acc, 1);
    acc += __shfl_xor(acc, 2);
    acc += __shfl_xor(acc, 4);
    acc += __shfl_xor(acc, 8);
    acc += __shfl_xor(acc, 16);
    acc += __shfl_xor(acc, 32);
    const int wave = threadIdx.x >> 6;
    const int lane = threadIdx.x & 63;
    if (lane == 0) red[wave] = acc;
    __syncthreads();
    if (threadIdx.x == 0)
        atomicAdd(out, (red[0] + red[1] + red[2] + red[3]) / (float)N);
}

extern "C" void kernel_launch(void* const* d_in, const int* in_sizes, int n_in,
                              void* d_out, int out_size, void* d_ws, size_t ws_size,
                              hipStream_t stream) {
    const float* x = (const float*)d_in[0];
    const int D = 256;
    const int N = in_sizes[0] / D;  // 8192
    const int B = N / 128;          // 64

    unsigned short* xf = (unsigned short*)d_ws;                 // 4 MB
    float* prowR = (float*)((char*)d_ws + (size_t)N * D * 2);   // 128 x N = 4 MB
    float* prowC = prowR + (size_t)128 * N;                     // 64 x N = 2 MB
    float* out = (float*)d_out;

    normalize_repack_kernel<<<N / 16, 256, 0, stream>>>(x, xf, out, N);

    const int T = B * (B + 1) / 2;  // 2080 upper-triangle tiles
    gemm_frag_kernel<<<T, 128, 0, stream>>>(xf, prowR, prowC, N);

    finalize_kernel<<<N / 256, 256, 0, stream>>>(prowR, prowC, out, N);
}